// Round 8
// baseline (90.010 us; speedup 1.0000x reference)
//
#include <hip/hip_runtime.h>
#include <math.h>

typedef _Float16 f16;
typedef _Float16 f16x8 __attribute__((ext_vector_type(8)));
typedef _Float16 f16x4 __attribute__((ext_vector_type(4)));
typedef float f32x4 __attribute__((ext_vector_type(4)));

#define BATCH 8
#define CHN   64
#define NPTS  8192
#define P2    192
#define GG    (P2 * P2)   // 36864
#define NCHG  32          // gram chunks per batch (256 pts each)

// ---------------------------------------------------------------------------
// k_mp: MS[c][c2][h] = sum_d Wq[h64+d][c]*Wk[h64+d][c2]   (h-contiguous float4)
//       P[h][o][c]   = sum_d Wout[o][h64+d]*Wv[h64+d][c]
// ---------------------------------------------------------------------------
__global__ __launch_bounds__(256) void k_mp(const float* __restrict__ Wq,
                                            const float* __restrict__ Wk,
                                            const float* __restrict__ Wv,
                                            const float* __restrict__ Wout,
                                            float* __restrict__ MS,
                                            float* __restrict__ P) {
    const int h     = blockIdx.x & 3;
    const int which = blockIdx.x >> 2;
    const int tid   = threadIdx.x;
    for (int e = 0; e < 16; e++) {
        int id = e * 256 + tid;          // id = r*64 + c2
        int r  = id >> 6, c2 = id & 63;
        float s = 0.0f;
        if (which == 0) {
#pragma unroll 8
            for (int d = 0; d < 64; d++)
                s += Wq[(h * 64 + d) * 64 + r] * Wk[(h * 64 + d) * 64 + c2];
            MS[(size_t)id * 4 + h] = s;
        } else {
#pragma unroll 8
            for (int d = 0; d < 64; d++)
                s += Wout[r * 256 + h * 64 + d] * Wv[(h * 64 + d) * 64 + c2];
            P[h * 4096 + id] = s;
        }
    }
}

// ---------------------------------------------------------------------------
// k_mx: MX[p2][q2][h] = MS[c(p2)][c2(q2)][h] — M broadcast into G-index space
// so the k_gram epilogue loads are dense 256-B coalesced segments.
// ---------------------------------------------------------------------------
__global__ __launch_bounds__(256) void k_mx(const float* __restrict__ MS,
                                            float* __restrict__ MX) {
    int i = blockIdx.x * 256 + threadIdx.x;      // GG entries (grid 144)
    if (i >= GG) return;
    int p = i / P2, q = i - p * P2;
    int c = p / 3, c2 = q / 3;
    *(f32x4*)(MX + (size_t)i * 4) = *(const f32x4*)(MS + (size_t)(c * 64 + c2) * 4);
}

// ---------------------------------------------------------------------------
// k_gram: K=256 pts per block, 8 waves (48x96 tile each), 4 x 64-pt phases,
// double-buffered LDS, 2-deep load pipeline (SA/SB statically named).
// Epilogue: contract G-tile vs MX into 36 logit partials (rotation buckets),
// SRED block-reduce, plain store. grid 256 = 8b x 32kc.   (unchanged from R7)
// ---------------------------------------------------------------------------
__global__ __launch_bounds__(512, 2) void k_gram(const float* __restrict__ feat,
                                                 const f32x4* __restrict__ MX,
                                                 float* __restrict__ pl) {
    const int kc  = blockIdx.x & (NCHG - 1);
    const int b   = blockIdx.x >> 5;
    const int n0  = kc * 256;
    const int tid = threadIdx.x;
    const int wid = tid >> 6, lane = tid & 63;
    const int l15 = lane & 15, l4 = lane >> 4;
    const int qd = wid & 3, strip = wid >> 2;
    const int qp = (qd >> 1) * 96 + strip * 48;   // 48-row strip base (mult of 3)
    const int qq = (qd & 1) * 96;

    __shared__ char smem[77184];   // Tbuf[2][192*128B]=49152  UNION  SRED[8][36][67]f32=77184
    __shared__ float fin[8][36];
    char* T0 = smem;
    char* T1 = smem + 24576;
    float (*SRED)[36][67] = (float (*)[36][67])smem;

    const float* fb = feat + (size_t)b * CHN * NPTS * 3;
    const int tc = tid >> 4;          // task channel base (0..31); task2 = +32
    const int g4 = (tid & 15) * 4;    // 4-pt group start
    const int g8 = (tid & 15) * 8;    // byte col of f16x4 in 128-B row

    f32x4 acc[3][6];
#pragma unroll
    for (int i = 0; i < 3; i++)
#pragma unroll
        for (int j = 0; j < 6; j++) acc[i][j] = (f32x4){0.f, 0.f, 0.f, 0.f};

    float4 SA[2][3], SB[2][3];

#define G_LOADS(S, nbase)                                                      \
    {                                                                          \
        _Pragma("unroll")                                                      \
        for (int ti = 0; ti < 2; ti++) {                                       \
            int c = tc + ti * 32;                                              \
            const float* src = fb + ((size_t)c * NPTS + (nbase) + g4) * 3;     \
            S[ti][0] = *(const float4*)(src);                                  \
            S[ti][1] = *(const float4*)(src + 4);                              \
            S[ti][2] = *(const float4*)(src + 8);                              \
        }                                                                      \
    }
#define G_WRITES(S, Tb)                                                        \
    {                                                                          \
        _Pragma("unroll")                                                      \
        for (int ti = 0; ti < 2; ti++) {                                       \
            int c = tc + ti * 32;                                              \
            float v[12] = {S[ti][0].x, S[ti][0].y, S[ti][0].z, S[ti][0].w,     \
                           S[ti][1].x, S[ti][1].y, S[ti][1].z, S[ti][1].w,     \
                           S[ti][2].x, S[ti][2].y, S[ti][2].z, S[ti][2].w};    \
            _Pragma("unroll")                                                  \
            for (int t = 0; t < 3; t++) {                                      \
                int row = c * 3 + t;                                           \
                f16x4 pk = {(f16)v[t], (f16)v[3 + t], (f16)v[6 + t],           \
                            (f16)v[9 + t]};                                    \
                int bo = (row * 128 + g8) ^ ((row & 7) << 4);                  \
                *(f16x4*)((Tb) + bo) = pk;                                     \
            }                                                                  \
        }                                                                      \
    }
#define G_COMPUTE(Tb)                                                          \
    {                                                                          \
        _Pragma("unroll")                                                      \
        for (int ks = 0; ks < 2; ks++) {                                       \
            f16x8 af[3], bf[6];                                                \
            _Pragma("unroll")                                                  \
            for (int mt = 0; mt < 3; mt++) {                                   \
                int row = qp + mt * 16 + l15;                                  \
                af[mt] = *(const f16x8*)((Tb) +                                \
                    ((row * 128 + ks * 64 + l4 * 16) ^ ((row & 7) << 4)));     \
            }                                                                  \
            _Pragma("unroll")                                                  \
            for (int nt = 0; nt < 6; nt++) {                                   \
                int row = qq + nt * 16 + l15;                                  \
                bf[nt] = *(const f16x8*)((Tb) +                                \
                    ((row * 128 + ks * 64 + l4 * 16) ^ ((row & 7) << 4)));     \
            }                                                                  \
            _Pragma("unroll")                                                  \
            for (int mt = 0; mt < 3; mt++)                                     \
                _Pragma("unroll")                                              \
                for (int nt = 0; nt < 6; nt++)                                 \
                    acc[mt][nt] = __builtin_amdgcn_mfma_f32_16x16x32_f16(      \
                        af[mt], bf[nt], acc[mt][nt], 0, 0, 0);                 \
        }                                                                      \
    }

    // prologue: stage phase 0, issue phase-1 loads
    G_LOADS(SA, n0);
    G_WRITES(SA, T0);
    G_LOADS(SB, n0 + 64);
    __syncthreads();
    // phase 0: compute T0; write phase1->T1; issue phase-2 loads
    G_COMPUTE(T0); G_WRITES(SB, T1); G_LOADS(SA, n0 + 128);
    __syncthreads();
    // phase 1: compute T1; write phase2->T0 (T0 last read phase 0, barrier between)
    G_COMPUTE(T1); G_WRITES(SA, T0); G_LOADS(SB, n0 + 192);
    __syncthreads();
    // phase 2
    G_COMPUTE(T0); G_WRITES(SB, T1);
    __syncthreads();
    // phase 3
    G_COMPUTE(T1);
    __syncthreads();    // all frag reads done before SRED aliases Tbuf

    // ---- logit contraction: true t=(mt+l4+r)%3, s=(nt+l15)%3 ----
    float l[36];
#pragma unroll
    for (int i = 0; i < 36; i++) l[i] = 0.0f;
#pragma unroll
    for (int mt = 0; mt < 3; mt++) {
#pragma unroll
        for (int r = 0; r < 4; r++) {
            int p = qp + mt * 16 + l4 * 4 + r;
            const f32x4* mxp = MX + (size_t)p * P2 + qq + l15;
#pragma unroll
            for (int nt = 0; nt < 6; nt++) {
                f32x4 ms = mxp[nt * 16];        // 4 heads, coalesced
                float g = acc[mt][nt][r];
                const int ts = ((mt + r) % 3) * 3 + (nt % 3);
                l[ts]      = fmaf(ms[0], g, l[ts]);
                l[9 + ts]  = fmaf(ms[1], g, l[9 + ts]);
                l[18 + ts] = fmaf(ms[2], g, l[18 + ts]);
                l[27 + ts] = fmaf(ms[3], g, l[27 + ts]);
            }
        }
    }
    const int pt = l4 % 3, ps = l15 % 3;
    int rowmap[9];
#pragma unroll
    for (int tt = 0; tt < 3; tt++)
#pragma unroll
        for (int ss = 0; ss < 3; ss++)
            rowmap[tt * 3 + ss] = ((tt + pt) % 3) * 3 + ((ss + ps) % 3);
#pragma unroll
    for (int h = 0; h < 4; h++)
#pragma unroll
        for (int i9 = 0; i9 < 9; i9++)
            SRED[wid][h * 9 + rowmap[i9]][lane] = l[h * 9 + i9];
    __syncthreads();
    if (tid < 288) {
        int w = tid / 36, row = tid - (tid / 36) * 36;
        float s = 0.0f;
#pragma unroll 8
        for (int col = 0; col < 64; col++) s += SRED[w][row][col];
        fin[w][row] = s;
    }
    __syncthreads();
    if (tid < 36) {
        float s = 0.0f;
#pragma unroll
        for (int w = 0; w < 8; w++) s += fin[w][tid];
        pl[(size_t)(b * NCHG + kc) * 36 + tid] = s;
    }
#undef G_LOADS
#undef G_WRITES
#undef G_COMPUTE
}

// ---------------------------------------------------------------------------
// k_abig: fused softmax + Ab build.  (unchanged)
// ---------------------------------------------------------------------------
__global__ __launch_bounds__(256) void k_abig(const float* __restrict__ pl,
                                              const float* __restrict__ P,
                                              f16* __restrict__ Ab) {
    const int blk = blockIdx.x;                // 1152 = 8 b x 144
    const int b   = blk / 144;
    const int tid = threadIdx.x;
    __shared__ float ls[36], wsm[36];
    if (tid < 36) {
        float s = 0.0f;
        for (int k = 0; k < NCHG; k++)
            s += pl[(size_t)(b * NCHG + k) * 36 + tid];
        ls[tid] = s * 0.07216878364870322f;    // 1/sqrt(192)
    }
    __syncthreads();
    if (tid < 36) {
        int base = (tid / 3) * 3;
        float z0 = ls[base], z1 = ls[base + 1], z2 = ls[base + 2];
        float mx = fmaxf(z0, fmaxf(z1, z2));
        float e0 = expf(z0 - mx), e1 = expf(z1 - mx), e2 = expf(z2 - mx);
        wsm[tid] = expf(ls[tid] - mx) / (e0 + e1 + e2);
    }
    __syncthreads();

    int i  = blk * 256 + tid;
    int rr = i - b * GG;
    int p2 = rr / P2, q2 = rr - p2 * P2;
    int o = p2 / 3, t = p2 - 3 * (p2 / 3);
    int c = q2 / 3, s = q2 - 3 * (q2 / 3);
    float acc = 0.0f;
#pragma unroll
    for (int h = 0; h < 4; h++)
        acc = fmaf(wsm[h * 9 + t * 3 + s], P[h * 4096 + o * 64 + c], acc);
    Ab[i] = (f16)acc;
}

// ---------------------------------------------------------------------------
// k_apply: out[b][o][n][t] = feat + sum_q2 Ab[p2][q2] * X[n][q2]
// 128-thr block (2 waves), 32-pt n-tile, grid 2048 -> 8 blocks/CU (2x the
// independent dependency chains of R7). Wave w: rows w*96..+95.
// ---------------------------------------------------------------------------
__global__ __launch_bounds__(128, 4) void k_apply(const float* __restrict__ feat,
                                                  const f16* __restrict__ Ab,
                                                  float* __restrict__ out) {
    const int nb  = blockIdx.x & 255;
    const int b   = blockIdx.x >> 8;
    const int n0  = nb * 32;
    const int tid = threadIdx.x;
    const int wid = tid >> 6, lane = tid & 63;
    const int l15 = lane & 15, l4 = lane >> 4;

    __shared__ f16 X[32 * 200];          // [nn][q2], padded 192->200 (12.8 KB)

    const float* fb = feat + (size_t)b * CHN * NPTS * 3;
    const f16* A = Ab + (size_t)b * GG;

    // stage: 64 ch x 32 pts x 3 = 1536 float4 / 128 thr
#pragma unroll
    for (int i = 0; i < 12; i++) {
        int idx = tid + i * 128;
        int c = idx / 24, j = idx - (idx / 24) * 24;
        float4 v = *(const float4*)(fb + ((size_t)c * NPTS + n0) * 3 + j * 4);
        float vv[4] = {v.x, v.y, v.z, v.w};
#pragma unroll
        for (int u = 0; u < 4; u++) {
            int e = j * 4 + u, nn = e / 3, s = e - 3 * (e / 3);
            X[nn * 200 + c * 3 + s] = (f16)vv[u];
        }
    }
    __syncthreads();

    f32x4 acc[6][2];
#pragma unroll
    for (int i = 0; i < 6; i++)
#pragma unroll
        for (int j = 0; j < 2; j++) acc[i][j] = (f32x4){0.f, 0.f, 0.f, 0.f};

#pragma unroll
    for (int ks = 0; ks < 6; ks++) {
        f16x8 af[6], bf[2];
#pragma unroll
        for (int mt = 0; mt < 6; mt++) {
            int p2 = wid * 96 + mt * 16 + l15;
            af[mt] = *(const f16x8*)(A + (size_t)p2 * P2 + ks * 32 + l4 * 8);
        }
#pragma unroll
        for (int nt = 0; nt < 2; nt++) {
            int nl = nt * 16 + l15;
            bf[nt] = *(const f16x8*)&X[nl * 200 + ks * 32 + l4 * 8];
        }
#pragma unroll
        for (int mt = 0; mt < 6; mt++)
#pragma unroll
            for (int nt = 0; nt < 2; nt++)
                acc[mt][nt] = __builtin_amdgcn_mfma_f32_16x16x32_f16(af[mt], bf[nt], acc[mt][nt], 0, 0, 0);
    }

    float* ob = out + (size_t)b * CHN * NPTS * 3;
#pragma unroll
    for (int mt = 0; mt < 6; mt++) {
        int p2b = wid * 96 + mt * 16 + l4 * 4;
#pragma unroll
        for (int nt = 0; nt < 2; nt++) {
            int nl = nt * 16 + l15;
            f16x4 rx = *(const f16x4*)&X[nl * 200 + p2b];
#pragma unroll
            for (int r = 0; r < 4; r++) {
                int p2 = p2b + r;
                int o = p2 / 3, t = p2 - 3 * (p2 / 3);
                ob[((size_t)o * NPTS + n0 + nl) * 3 + t] = (float)rx[r] + acc[mt][nt][r];
            }
        }
    }
}

extern "C" void kernel_launch(void* const* d_in, const int* in_sizes, int n_in,
                              void* d_out, int out_size, void* d_ws, size_t ws_size,
                              hipStream_t stream) {
    const float* feat = (const float*)d_in[0];
    const float* Wq   = (const float*)d_in[2];
    const float* Wk   = (const float*)d_in[3];
    const float* Wv   = (const float*)d_in[4];
    const float* Wout = (const float*)d_in[5];
    float* out = (float*)d_out;

    char* w8 = (char*)d_ws;                    // total ws use: ~1.35 MB
    f16*   Ab = (f16*)w8;                      //   589,824 B
    float* MS = (float*)(w8 + 589824);         //    65,536 B
    float* P  = (float*)(w8 + 655360);         //    65,536 B
    float* MX = (float*)(w8 + 720896);         //   589,824 B
    float* pl = (float*)(w8 + 1310720);        //    36,864 B

    k_mp   <<<8,            256, 0, stream>>>(Wq, Wk, Wv, Wout, MS, P);
    k_mx   <<<144,          256, 0, stream>>>(MS, MX);
    k_gram <<<BATCH * NCHG, 512, 0, stream>>>(feat, (const f32x4*)MX, pl);
    k_abig <<<1152,         256, 0, stream>>>(pl, P, Ab);
    k_apply<<<2048,         128, 0, stream>>>(feat, Ab, out);
}

// Round 9
// 82.374 us; speedup vs baseline: 1.0927x; 1.0927x over previous
//
#include <hip/hip_runtime.h>
#include <math.h>

typedef _Float16 f16;
typedef _Float16 f16x8 __attribute__((ext_vector_type(8)));
typedef _Float16 f16x4 __attribute__((ext_vector_type(4)));
typedef float f32x4 __attribute__((ext_vector_type(4)));

#define BATCH 8
#define CHN   64
#define NPTS  8192
#define P2    192
#define GG    (P2 * P2)   // 36864
#define NCHG  32          // gram chunks per batch (256 pts each)

// ---------------------------------------------------------------------------
// k_mp: MS[c][c2][h] = sum_d Wq[h64+d][c]*Wk[h64+d][c2]   (h-contiguous float4)
//       P[h][o][c]   = sum_d Wout[o][h64+d]*Wv[h64+d][c]
// ---------------------------------------------------------------------------
__global__ __launch_bounds__(256) void k_mp(const float* __restrict__ Wq,
                                            const float* __restrict__ Wk,
                                            const float* __restrict__ Wv,
                                            const float* __restrict__ Wout,
                                            float* __restrict__ MS,
                                            float* __restrict__ P) {
    const int h     = blockIdx.x & 3;
    const int which = blockIdx.x >> 2;
    const int tid   = threadIdx.x;
    for (int e = 0; e < 16; e++) {
        int id = e * 256 + tid;          // id = r*64 + c2
        int r  = id >> 6, c2 = id & 63;
        float s = 0.0f;
        if (which == 0) {
#pragma unroll 8
            for (int d = 0; d < 64; d++)
                s += Wq[(h * 64 + d) * 64 + r] * Wk[(h * 64 + d) * 64 + c2];
            MS[(size_t)id * 4 + h] = s;
        } else {
#pragma unroll 8
            for (int d = 0; d < 64; d++)
                s += Wout[r * 256 + h * 64 + d] * Wv[(h * 64 + d) * 64 + c2];
            P[h * 4096 + id] = s;
        }
    }
}

// ---------------------------------------------------------------------------
// k_mx: MX[p2][q2][h] = MS[c(p2)][c2(q2)][h]
// ---------------------------------------------------------------------------
__global__ __launch_bounds__(256) void k_mx(const float* __restrict__ MS,
                                            float* __restrict__ MX) {
    int i = blockIdx.x * 256 + threadIdx.x;      // GG entries (grid 144)
    if (i >= GG) return;
    int p = i / P2, q = i - p * P2;
    int c = p / 3, c2 = q / 3;
    *(f32x4*)(MX + (size_t)i * 4) = *(const f32x4*)(MS + (size_t)(c * 64 + c2) * 4);
}

// ---------------------------------------------------------------------------
// k_gram: unchanged from R7 (K=256/block, 8 waves, dbuf LDS, logit epilogue)
// ---------------------------------------------------------------------------
__global__ __launch_bounds__(512, 2) void k_gram(const float* __restrict__ feat,
                                                 const f32x4* __restrict__ MX,
                                                 float* __restrict__ pl) {
    const int kc  = blockIdx.x & (NCHG - 1);
    const int b   = blockIdx.x >> 5;
    const int n0  = kc * 256;
    const int tid = threadIdx.x;
    const int wid = tid >> 6, lane = tid & 63;
    const int l15 = lane & 15, l4 = lane >> 4;
    const int qd = wid & 3, strip = wid >> 2;
    const int qp = (qd >> 1) * 96 + strip * 48;   // 48-row strip base (mult of 3)
    const int qq = (qd & 1) * 96;

    __shared__ char smem[77184];   // Tbuf[2][192*128B]=49152  UNION  SRED[8][36][67]f32
    __shared__ float fin[8][36];
    char* T0 = smem;
    char* T1 = smem + 24576;
    float (*SRED)[36][67] = (float (*)[36][67])smem;

    const float* fb = feat + (size_t)b * CHN * NPTS * 3;
    const int tc = tid >> 4;
    const int g4 = (tid & 15) * 4;
    const int g8 = (tid & 15) * 8;

    f32x4 acc[3][6];
#pragma unroll
    for (int i = 0; i < 3; i++)
#pragma unroll
        for (int j = 0; j < 6; j++) acc[i][j] = (f32x4){0.f, 0.f, 0.f, 0.f};

    float4 SA[2][3], SB[2][3];

#define G_LOADS(S, nbase)                                                      \
    {                                                                          \
        _Pragma("unroll")                                                      \
        for (int ti = 0; ti < 2; ti++) {                                       \
            int c = tc + ti * 32;                                              \
            const float* src = fb + ((size_t)c * NPTS + (nbase) + g4) * 3;     \
            S[ti][0] = *(const float4*)(src);                                  \
            S[ti][1] = *(const float4*)(src + 4);                              \
            S[ti][2] = *(const float4*)(src + 8);                              \
        }                                                                      \
    }
#define G_WRITES(S, Tb)                                                        \
    {                                                                          \
        _Pragma("unroll")                                                      \
        for (int ti = 0; ti < 2; ti++) {                                       \
            int c = tc + ti * 32;                                              \
            float v[12] = {S[ti][0].x, S[ti][0].y, S[ti][0].z, S[ti][0].w,     \
                           S[ti][1].x, S[ti][1].y, S[ti][1].z, S[ti][1].w,     \
                           S[ti][2].x, S[ti][2].y, S[ti][2].z, S[ti][2].w};    \
            _Pragma("unroll")                                                  \
            for (int t = 0; t < 3; t++) {                                      \
                int row = c * 3 + t;                                           \
                f16x4 pk = {(f16)v[t], (f16)v[3 + t], (f16)v[6 + t],           \
                            (f16)v[9 + t]};                                    \
                int bo = (row * 128 + g8) ^ ((row & 7) << 4);                  \
                *(f16x4*)((Tb) + bo) = pk;                                     \
            }                                                                  \
        }                                                                      \
    }
#define G_COMPUTE(Tb)                                                          \
    {                                                                          \
        _Pragma("unroll")                                                      \
        for (int ks = 0; ks < 2; ks++) {                                       \
            f16x8 af[3], bf[6];                                                \
            _Pragma("unroll")                                                  \
            for (int mt = 0; mt < 3; mt++) {                                   \
                int row = qp + mt * 16 + l15;                                  \
                af[mt] = *(const f16x8*)((Tb) +                                \
                    ((row * 128 + ks * 64 + l4 * 16) ^ ((row & 7) << 4)));     \
            }                                                                  \
            _Pragma("unroll")                                                  \
            for (int nt = 0; nt < 6; nt++) {                                   \
                int row = qq + nt * 16 + l15;                                  \
                bf[nt] = *(const f16x8*)((Tb) +                                \
                    ((row * 128 + ks * 64 + l4 * 16) ^ ((row & 7) << 4)));     \
            }                                                                  \
            _Pragma("unroll")                                                  \
            for (int mt = 0; mt < 3; mt++)                                     \
                _Pragma("unroll")                                              \
                for (int nt = 0; nt < 6; nt++)                                 \
                    acc[mt][nt] = __builtin_amdgcn_mfma_f32_16x16x32_f16(      \
                        af[mt], bf[nt], acc[mt][nt], 0, 0, 0);                 \
        }                                                                      \
    }

    G_LOADS(SA, n0);
    G_WRITES(SA, T0);
    G_LOADS(SB, n0 + 64);
    __syncthreads();
    G_COMPUTE(T0); G_WRITES(SB, T1); G_LOADS(SA, n0 + 128);
    __syncthreads();
    G_COMPUTE(T1); G_WRITES(SA, T0); G_LOADS(SB, n0 + 192);
    __syncthreads();
    G_COMPUTE(T0); G_WRITES(SB, T1);
    __syncthreads();
    G_COMPUTE(T1);
    __syncthreads();

    float l[36];
#pragma unroll
    for (int i = 0; i < 36; i++) l[i] = 0.0f;
#pragma unroll
    for (int mt = 0; mt < 3; mt++) {
#pragma unroll
        for (int r = 0; r < 4; r++) {
            int p = qp + mt * 16 + l4 * 4 + r;
            const f32x4* mxp = MX + (size_t)p * P2 + qq + l15;
#pragma unroll
            for (int nt = 0; nt < 6; nt++) {
                f32x4 ms = mxp[nt * 16];
                float g = acc[mt][nt][r];
                const int ts = ((mt + r) % 3) * 3 + (nt % 3);
                l[ts]      = fmaf(ms[0], g, l[ts]);
                l[9 + ts]  = fmaf(ms[1], g, l[9 + ts]);
                l[18 + ts] = fmaf(ms[2], g, l[18 + ts]);
                l[27 + ts] = fmaf(ms[3], g, l[27 + ts]);
            }
        }
    }
    const int pt = l4 % 3, ps = l15 % 3;
    int rowmap[9];
#pragma unroll
    for (int tt = 0; tt < 3; tt++)
#pragma unroll
        for (int ss = 0; ss < 3; ss++)
            rowmap[tt * 3 + ss] = ((tt + pt) % 3) * 3 + ((ss + ps) % 3);
#pragma unroll
    for (int h = 0; h < 4; h++)
#pragma unroll
        for (int i9 = 0; i9 < 9; i9++)
            SRED[wid][h * 9 + rowmap[i9]][lane] = l[h * 9 + i9];
    __syncthreads();
    if (tid < 288) {
        int w = tid / 36, row = tid - (tid / 36) * 36;
        float s = 0.0f;
#pragma unroll 8
        for (int col = 0; col < 64; col++) s += SRED[w][row][col];
        fin[w][row] = s;
    }
    __syncthreads();
    if (tid < 36) {
        float s = 0.0f;
#pragma unroll
        for (int w = 0; w < 8; w++) s += fin[w][tid];
        pl[(size_t)(b * NCHG + kc) * 36 + tid] = s;
    }
#undef G_LOADS
#undef G_WRITES
#undef G_COMPUTE
}

// ---------------------------------------------------------------------------
// k_abig: fused softmax + Ab build.  (unchanged)
// ---------------------------------------------------------------------------
__global__ __launch_bounds__(256) void k_abig(const float* __restrict__ pl,
                                              const float* __restrict__ P,
                                              f16* __restrict__ Ab) {
    const int blk = blockIdx.x;                // 1152 = 8 b x 144
    const int b   = blk / 144;
    const int tid = threadIdx.x;
    __shared__ float ls[36], wsm[36];
    if (tid < 36) {
        float s = 0.0f;
        for (int k = 0; k < NCHG; k++)
            s += pl[(size_t)(b * NCHG + k) * 36 + tid];
        ls[tid] = s * 0.07216878364870322f;    // 1/sqrt(192)
    }
    __syncthreads();
    if (tid < 36) {
        int base = (tid / 3) * 3;
        float z0 = ls[base], z1 = ls[base + 1], z2 = ls[base + 2];
        float mx = fmaxf(z0, fmaxf(z1, z2));
        float e0 = expf(z0 - mx), e1 = expf(z1 - mx), e2 = expf(z2 - mx);
        wsm[tid] = expf(ls[tid] - mx) / (e0 + e1 + e2);
    }
    __syncthreads();

    int i  = blk * 256 + tid;
    int rr = i - b * GG;
    int p2 = rr / P2, q2 = rr - p2 * P2;
    int o = p2 / 3, t = p2 - 3 * (p2 / 3);
    int c = q2 / 3, s = q2 - 3 * (q2 / 3);
    float acc = 0.0f;
#pragma unroll
    for (int h = 0; h < 4; h++)
        acc = fmaf(wsm[h * 9 + t * 3 + s], P[h * 4096 + o * 64 + c], acc);
    Ab[i] = (f16)acc;
}

// ---------------------------------------------------------------------------
// k_apply: out[b][o][n][t] = feat + sum_q2 Ab[p2][q2] * X[n][q2]
// Register-resident Ab: 4 waves x 48 p2-rows, af[6][3] preloaded once.
// 128 pts/block (2 x 64-pt sub-tiles), double-buffered XOR-swizzled LDS X.
// grid 512 = 8b x 64 chunks.
// ---------------------------------------------------------------------------
__global__ __launch_bounds__(256, 2) void k_apply(const float* __restrict__ feat,
                                                  const f16* __restrict__ Ab,
                                                  float* __restrict__ out) {
    const int nb  = blockIdx.x & 63;
    const int b   = blockIdx.x >> 6;
    const int n0  = nb * 128;
    const int tid = threadIdx.x;
    const int wid = tid >> 6, lane = tid & 63;
    const int l15 = lane & 15, l4 = lane >> 4;

    __shared__ char xs[2][24576];        // [buf][64 rows nn x 384 B], XOR-swizzled

    const float* fb = feat + (size_t)b * CHN * NPTS * 3;
    const f16*   A  = Ab + (size_t)b * GG;
    float*       ob = out + (size_t)b * CHN * NPTS * 3;

    // staging macros: 64 ch x 64 pts x 3 = 3072 float4 / 256 thr (12/thread)
#define A_LOADS(S, nbase)                                                      \
    {                                                                          \
        _Pragma("unroll")                                                      \
        for (int i = 0; i < 12; i++) {                                         \
            int idx = tid + i * 256;                                           \
            int c = idx / 48, j = idx - (idx / 48) * 48;                       \
            S[i] = *(const float4*)(fb + ((size_t)c * NPTS + (nbase)) * 3 + j * 4); \
        }                                                                      \
    }
#define A_WRITES(S, Xb)                                                        \
    {                                                                          \
        _Pragma("unroll")                                                      \
        for (int i = 0; i < 12; i++) {                                         \
            int idx = tid + i * 256;                                           \
            int c = idx / 48, j = idx - (idx / 48) * 48;                       \
            float vv[4] = {S[i].x, S[i].y, S[i].z, S[i].w};                    \
            _Pragma("unroll")                                                  \
            for (int u = 0; u < 4; u++) {                                      \
                int e = j * 4 + u, nn = e / 3, s = e - 3 * (e / 3);            \
                int bo = (nn * 384 + (c * 3 + s) * 2) ^ ((nn & 7) << 4);       \
                *(f16*)((Xb) + bo) = (f16)vv[u];                               \
            }                                                                  \
        }                                                                      \
    }
#define A_COMPUTE(Xb, acc)                                                     \
    {                                                                          \
        _Pragma("unroll")                                                      \
        for (int ks = 0; ks < 6; ks++) {                                       \
            f16x8 bf[4];                                                       \
            _Pragma("unroll")                                                  \
            for (int nt = 0; nt < 4; nt++) {                                   \
                int nl = nt * 16 + l15;                                        \
                bf[nt] = *(const f16x8*)((Xb) +                                \
                    ((nl * 384 + ks * 64 + l4 * 16) ^ ((nl & 7) << 4)));       \
            }                                                                  \
            _Pragma("unroll")                                                  \
            for (int mt = 0; mt < 3; mt++)                                     \
                _Pragma("unroll")                                              \
                for (int nt = 0; nt < 4; nt++)                                 \
                    acc[mt][nt] = __builtin_amdgcn_mfma_f32_16x16x32_f16(      \
                        af[ks][mt], bf[nt], acc[mt][nt], 0, 0, 0);             \
        }                                                                      \
    }
#define A_EPI(Xb, acc, nsub)                                                   \
    {                                                                          \
        _Pragma("unroll")                                                      \
        for (int mt = 0; mt < 3; mt++) {                                       \
            int p2b = wid * 48 + mt * 16 + l4 * 4;                             \
            _Pragma("unroll")                                                  \
            for (int nt = 0; nt < 4; nt++) {                                   \
                int nl = nt * 16 + l15;                                        \
                f16x4 rx = *(const f16x4*)((Xb) +                              \
                    ((nl * 384 + p2b * 2) ^ ((nl & 7) << 4)));                 \
                _Pragma("unroll")                                              \
                for (int r = 0; r < 4; r++) {                                  \
                    int p2 = p2b + r;                                          \
                    int o = p2 / 3, t = p2 - 3 * (p2 / 3);                     \
                    ob[((size_t)o * NPTS + (nsub) + nl) * 3 + t]               \
                        = (float)rx[r] + acc[mt][nt][r];                       \
                }                                                              \
            }                                                                  \
        }                                                                      \
    }

    float4 S0[12], S1[12];
    A_LOADS(S0, n0);

    // preload A-fragments (register-resident across whole block)
    f16x8 af[6][3];
#pragma unroll
    for (int ks = 0; ks < 6; ks++)
#pragma unroll
        for (int mt = 0; mt < 3; mt++) {
            int p2 = wid * 48 + mt * 16 + l15;
            af[ks][mt] = *(const f16x8*)(A + (size_t)p2 * P2 + ks * 32 + l4 * 8);
        }

    A_WRITES(S0, xs[0]);
    A_LOADS(S1, n0 + 64);
    __syncthreads();

    f32x4 acc0[3][4];
#pragma unroll
    for (int i = 0; i < 3; i++)
#pragma unroll
        for (int j = 0; j < 4; j++) acc0[i][j] = (f32x4){0.f, 0.f, 0.f, 0.f};
    A_COMPUTE(xs[0], acc0);
    A_WRITES(S1, xs[1]);
    A_EPI(xs[0], acc0, n0);
    __syncthreads();

    f32x4 acc1[3][4];
#pragma unroll
    for (int i = 0; i < 3; i++)
#pragma unroll
        for (int j = 0; j < 4; j++) acc1[i][j] = (f32x4){0.f, 0.f, 0.f, 0.f};
    A_COMPUTE(xs[1], acc1);
    A_EPI(xs[1], acc1, n0 + 64);
#undef A_LOADS
#undef A_WRITES
#undef A_COMPUTE
#undef A_EPI
}

extern "C" void kernel_launch(void* const* d_in, const int* in_sizes, int n_in,
                              void* d_out, int out_size, void* d_ws, size_t ws_size,
                              hipStream_t stream) {
    const float* feat = (const float*)d_in[0];
    const float* Wq   = (const float*)d_in[2];
    const float* Wk   = (const float*)d_in[3];
    const float* Wv   = (const float*)d_in[4];
    const float* Wout = (const float*)d_in[5];
    float* out = (float*)d_out;

    char* w8 = (char*)d_ws;                    // total ws use: ~1.35 MB
    f16*   Ab = (f16*)w8;                      //   589,824 B
    float* MS = (float*)(w8 + 589824);         //    65,536 B
    float* P  = (float*)(w8 + 655360);         //    65,536 B
    float* MX = (float*)(w8 + 720896);         //   589,824 B
    float* pl = (float*)(w8 + 1310720);        //    36,864 B

    k_mp   <<<8,            256, 0, stream>>>(Wq, Wk, Wv, Wout, MS, P);
    k_mx   <<<144,          256, 0, stream>>>(MS, MX);
    k_gram <<<BATCH * NCHG, 512, 0, stream>>>(feat, (const f32x4*)MX, pl);
    k_abig <<<1152,         256, 0, stream>>>(pl, P, Ab);
    k_apply<<<512,          256, 0, stream>>>(feat, Ab, out);
}

// Round 10
// 79.083 us; speedup vs baseline: 1.1382x; 1.0416x over previous
//
#include <hip/hip_runtime.h>
#include <math.h>

typedef _Float16 f16;
typedef _Float16 f16x8 __attribute__((ext_vector_type(8)));
typedef _Float16 f16x4 __attribute__((ext_vector_type(4)));
typedef float f32x4 __attribute__((ext_vector_type(4)));

#define BATCH 8
#define CHN   64
#define NPTS  8192
#define P2    192
#define GG    (P2 * P2)   // 36864
#define NCHG  32          // gram chunks per batch (256 pts each)

// ---------------------------------------------------------------------------
// k_mp: MS[c][c2][h] = sum_d Wq[h64+d][c]*Wk[h64+d][c2]   (h-contiguous float4)
//       P[h][o][c]   = sum_d Wout[o][h64+d]*Wv[h64+d][c]
// ---------------------------------------------------------------------------
__global__ __launch_bounds__(256) void k_mp(const float* __restrict__ Wq,
                                            const float* __restrict__ Wk,
                                            const float* __restrict__ Wv,
                                            const float* __restrict__ Wout,
                                            float* __restrict__ MS,
                                            float* __restrict__ P) {
    const int h     = blockIdx.x & 3;
    const int which = blockIdx.x >> 2;
    const int tid   = threadIdx.x;
    for (int e = 0; e < 16; e++) {
        int id = e * 256 + tid;          // id = r*64 + c2
        int r  = id >> 6, c2 = id & 63;
        float s = 0.0f;
        if (which == 0) {
#pragma unroll 8
            for (int d = 0; d < 64; d++)
                s += Wq[(h * 64 + d) * 64 + r] * Wk[(h * 64 + d) * 64 + c2];
            MS[(size_t)id * 4 + h] = s;
        } else {
#pragma unroll 8
            for (int d = 0; d < 64; d++)
                s += Wout[r * 256 + h * 64 + d] * Wv[(h * 64 + d) * 64 + c2];
            P[h * 4096 + id] = s;
        }
    }
}

// ---------------------------------------------------------------------------
// k_mx: MX[p2][q2][h] = MS[c(p2)][c2(q2)][h]
// ---------------------------------------------------------------------------
__global__ __launch_bounds__(256) void k_mx(const float* __restrict__ MS,
                                            float* __restrict__ MX) {
    int i = blockIdx.x * 256 + threadIdx.x;      // GG entries (grid 144)
    if (i >= GG) return;
    int p = i / P2, q = i - p * P2;
    int c = p / 3, c2 = q / 3;
    *(f32x4*)(MX + (size_t)i * 4) = *(const f32x4*)(MS + (size_t)(c * 64 + c2) * 4);
}

// ---------------------------------------------------------------------------
// k_gram: unchanged from R7 (K=256/block, 8 waves, dbuf LDS, logit epilogue)
// ---------------------------------------------------------------------------
__global__ __launch_bounds__(512, 2) void k_gram(const float* __restrict__ feat,
                                                 const f32x4* __restrict__ MX,
                                                 float* __restrict__ pl) {
    const int kc  = blockIdx.x & (NCHG - 1);
    const int b   = blockIdx.x >> 5;
    const int n0  = kc * 256;
    const int tid = threadIdx.x;
    const int wid = tid >> 6, lane = tid & 63;
    const int l15 = lane & 15, l4 = lane >> 4;
    const int qd = wid & 3, strip = wid >> 2;
    const int qp = (qd >> 1) * 96 + strip * 48;
    const int qq = (qd & 1) * 96;

    __shared__ char smem[77184];
    __shared__ float fin[8][36];
    char* T0 = smem;
    char* T1 = smem + 24576;
    float (*SRED)[36][67] = (float (*)[36][67])smem;

    const float* fb = feat + (size_t)b * CHN * NPTS * 3;
    const int tc = tid >> 4;
    const int g4 = (tid & 15) * 4;
    const int g8 = (tid & 15) * 8;

    f32x4 acc[3][6];
#pragma unroll
    for (int i = 0; i < 3; i++)
#pragma unroll
        for (int j = 0; j < 6; j++) acc[i][j] = (f32x4){0.f, 0.f, 0.f, 0.f};

    float4 SA[2][3], SB[2][3];

#define G_LOADS(S, nbase)                                                      \
    {                                                                          \
        _Pragma("unroll")                                                      \
        for (int ti = 0; ti < 2; ti++) {                                       \
            int c = tc + ti * 32;                                              \
            const float* src = fb + ((size_t)c * NPTS + (nbase) + g4) * 3;     \
            S[ti][0] = *(const float4*)(src);                                  \
            S[ti][1] = *(const float4*)(src + 4);                              \
            S[ti][2] = *(const float4*)(src + 8);                              \
        }                                                                      \
    }
#define G_WRITES(S, Tb)                                                        \
    {                                                                          \
        _Pragma("unroll")                                                      \
        for (int ti = 0; ti < 2; ti++) {                                       \
            int c = tc + ti * 32;                                              \
            float v[12] = {S[ti][0].x, S[ti][0].y, S[ti][0].z, S[ti][0].w,     \
                           S[ti][1].x, S[ti][1].y, S[ti][1].z, S[ti][1].w,     \
                           S[ti][2].x, S[ti][2].y, S[ti][2].z, S[ti][2].w};    \
            _Pragma("unroll")                                                  \
            for (int t = 0; t < 3; t++) {                                      \
                int row = c * 3 + t;                                           \
                f16x4 pk = {(f16)v[t], (f16)v[3 + t], (f16)v[6 + t],           \
                            (f16)v[9 + t]};                                    \
                int bo = (row * 128 + g8) ^ ((row & 7) << 4);                  \
                *(f16x4*)((Tb) + bo) = pk;                                     \
            }                                                                  \
        }                                                                      \
    }
#define G_COMPUTE(Tb)                                                          \
    {                                                                          \
        _Pragma("unroll")                                                      \
        for (int ks = 0; ks < 2; ks++) {                                       \
            f16x8 af[3], bf[6];                                                \
            _Pragma("unroll")                                                  \
            for (int mt = 0; mt < 3; mt++) {                                   \
                int row = qp + mt * 16 + l15;                                  \
                af[mt] = *(const f16x8*)((Tb) +                                \
                    ((row * 128 + ks * 64 + l4 * 16) ^ ((row & 7) << 4)));     \
            }                                                                  \
            _Pragma("unroll")                                                  \
            for (int nt = 0; nt < 6; nt++) {                                   \
                int row = qq + nt * 16 + l15;                                  \
                bf[nt] = *(const f16x8*)((Tb) +                                \
                    ((row * 128 + ks * 64 + l4 * 16) ^ ((row & 7) << 4)));     \
            }                                                                  \
            _Pragma("unroll")                                                  \
            for (int mt = 0; mt < 3; mt++)                                     \
                _Pragma("unroll")                                              \
                for (int nt = 0; nt < 6; nt++)                                 \
                    acc[mt][nt] = __builtin_amdgcn_mfma_f32_16x16x32_f16(      \
                        af[mt], bf[nt], acc[mt][nt], 0, 0, 0);                 \
        }                                                                      \
    }

    G_LOADS(SA, n0);
    G_WRITES(SA, T0);
    G_LOADS(SB, n0 + 64);
    __syncthreads();
    G_COMPUTE(T0); G_WRITES(SB, T1); G_LOADS(SA, n0 + 128);
    __syncthreads();
    G_COMPUTE(T1); G_WRITES(SA, T0); G_LOADS(SB, n0 + 192);
    __syncthreads();
    G_COMPUTE(T0); G_WRITES(SB, T1);
    __syncthreads();
    G_COMPUTE(T1);
    __syncthreads();

    float l[36];
#pragma unroll
    for (int i = 0; i < 36; i++) l[i] = 0.0f;
#pragma unroll
    for (int mt = 0; mt < 3; mt++) {
#pragma unroll
        for (int r = 0; r < 4; r++) {
            int p = qp + mt * 16 + l4 * 4 + r;
            const f32x4* mxp = MX + (size_t)p * P2 + qq + l15;
#pragma unroll
            for (int nt = 0; nt < 6; nt++) {
                f32x4 ms = mxp[nt * 16];
                float g = acc[mt][nt][r];
                const int ts = ((mt + r) % 3) * 3 + (nt % 3);
                l[ts]      = fmaf(ms[0], g, l[ts]);
                l[9 + ts]  = fmaf(ms[1], g, l[9 + ts]);
                l[18 + ts] = fmaf(ms[2], g, l[18 + ts]);
                l[27 + ts] = fmaf(ms[3], g, l[27 + ts]);
            }
        }
    }
    const int pt = l4 % 3, ps = l15 % 3;
    int rowmap[9];
#pragma unroll
    for (int tt = 0; tt < 3; tt++)
#pragma unroll
        for (int ss = 0; ss < 3; ss++)
            rowmap[tt * 3 + ss] = ((tt + pt) % 3) * 3 + ((ss + ps) % 3);
#pragma unroll
    for (int h = 0; h < 4; h++)
#pragma unroll
        for (int i9 = 0; i9 < 9; i9++)
            SRED[wid][h * 9 + rowmap[i9]][lane] = l[h * 9 + i9];
    __syncthreads();
    if (tid < 288) {
        int w = tid / 36, row = tid - (tid / 36) * 36;
        float s = 0.0f;
#pragma unroll 8
        for (int col = 0; col < 64; col++) s += SRED[w][row][col];
        fin[w][row] = s;
    }
    __syncthreads();
    if (tid < 36) {
        float s = 0.0f;
#pragma unroll
        for (int w = 0; w < 8; w++) s += fin[w][tid];
        pl[(size_t)(b * NCHG + kc) * 36 + tid] = s;
    }
#undef G_LOADS
#undef G_WRITES
#undef G_COMPUTE
}

// ---------------------------------------------------------------------------
// k_abig: fused softmax + Ab build, identity FOLDED IN (residual in-matrix).
// ---------------------------------------------------------------------------
__global__ __launch_bounds__(256) void k_abig(const float* __restrict__ pl,
                                              const float* __restrict__ P,
                                              f16* __restrict__ Ab) {
    const int blk = blockIdx.x;                // 1152 = 8 b x 144
    const int b   = blk / 144;
    const int tid = threadIdx.x;
    __shared__ float ls[36], wsm[36];
    if (tid < 36) {
        float s = 0.0f;
        for (int k = 0; k < NCHG; k++)
            s += pl[(size_t)(b * NCHG + k) * 36 + tid];
        ls[tid] = s * 0.07216878364870322f;    // 1/sqrt(192)
    }
    __syncthreads();
    if (tid < 36) {
        int base = (tid / 3) * 3;
        float z0 = ls[base], z1 = ls[base + 1], z2 = ls[base + 2];
        float mx = fmaxf(z0, fmaxf(z1, z2));
        float e0 = expf(z0 - mx), e1 = expf(z1 - mx), e2 = expf(z2 - mx);
        wsm[tid] = expf(ls[tid] - mx) / (e0 + e1 + e2);
    }
    __syncthreads();

    int i  = blk * 256 + tid;
    int rr = i - b * GG;
    int p2 = rr / P2, q2 = rr - p2 * P2;
    int o = p2 / 3, t = p2 - 3 * (p2 / 3);
    int c = q2 / 3, s = q2 - 3 * (q2 / 3);
    float acc = (p2 == q2) ? 1.0f : 0.0f;      // identity folded
#pragma unroll
    for (int h = 0; h < 4; h++)
        acc = fmaf(wsm[h * 9 + t * 3 + s], P[h * 4096 + o * 64 + c], acc);
    Ab[i] = (f16)acc;
}

// ---------------------------------------------------------------------------
// k_apply v4: out = Ab(+I) * X, stores made contiguous via LDS out-tile.
// Phases: stage X[64][q2] f16 (400B rows) -> barrier -> 2-deep-pipelined
// af loads + MFMA -> barrier -> acc -> OT2[o][nn*3+t] f32 -> barrier ->
// 12 dense float4 stores/thread (768B runs per o-row).
// grid 1024 = 8b x 128 chunks (64 pts).
// ---------------------------------------------------------------------------
__global__ __launch_bounds__(256, 2) void k_apply(const float* __restrict__ feat,
                                                  const f16* __restrict__ Ab,
                                                  float* __restrict__ out) {
    const int nb  = blockIdx.x & 127;
    const int b   = blockIdx.x >> 7;
    const int n0  = nb * 64;
    const int tid = threadIdx.x;
    const int wid = tid >> 6, lane = tid & 63;
    const int l15 = lane & 15, l4 = lane >> 4;

    __shared__ char lds[50176];          // X: 64 rows x 400B (25.6K)  then  OT2: 64 x 784B

    const float* fb = feat + (size_t)b * CHN * NPTS * 3;
    const f16*   A  = Ab + (size_t)b * GG;
    float*       ob = out + (size_t)b * CHN * NPTS * 3;

    // ---- phase 0: stage X[nn][q2] fp16 (row stride 400 B) ----
    {
        float4 S[12];
#pragma unroll
        for (int i = 0; i < 12; i++) {
            int idx = tid + i * 256;
            int c = idx / 48, j = idx - (idx / 48) * 48;
            S[i] = *(const float4*)(fb + ((size_t)c * NPTS + n0) * 3 + j * 4);
        }
#pragma unroll
        for (int i = 0; i < 12; i++) {
            int idx = tid + i * 256;
            int c = idx / 48, j = idx - (idx / 48) * 48;
            float vv[4] = {S[i].x, S[i].y, S[i].z, S[i].w};
#pragma unroll
            for (int u = 0; u < 4; u++) {
                int e = j * 4 + u, nn = e / 3, s = e - 3 * (e / 3);
                *(f16*)(lds + nn * 400 + (c * 3 + s) * 2) = (f16)vv[u];
            }
        }
    }
    __syncthreads();

    // ---- phase 1: MFMA with 2-deep pipelined A-fragment loads ----
    f32x4 acc[3][4];
#pragma unroll
    for (int i = 0; i < 3; i++)
#pragma unroll
        for (int j = 0; j < 4; j++) acc[i][j] = (f32x4){0.f, 0.f, 0.f, 0.f};

    f16x8 afA[3], afB[3];
    const int prow = wid * 48 + l15;     // +mt*16 added per frag

#define LOAD_AF(dst, ks)                                                       \
    {                                                                          \
        _Pragma("unroll")                                                      \
        for (int mt = 0; mt < 3; mt++)                                         \
            dst[mt] = *(const f16x8*)(A + (size_t)(prow + mt * 16) * P2        \
                                        + (ks) * 32 + l4 * 8);                 \
    }
#define DO_MFMA(src, ks)                                                       \
    {                                                                          \
        f16x8 bf[4];                                                           \
        _Pragma("unroll")                                                      \
        for (int nt = 0; nt < 4; nt++) {                                       \
            int nl = nt * 16 + l15;                                            \
            bf[nt] = *(const f16x8*)(lds + nl * 400 + (ks) * 64 + l4 * 16);    \
        }                                                                      \
        _Pragma("unroll")                                                      \
        for (int mt = 0; mt < 3; mt++)                                         \
            _Pragma("unroll")                                                  \
            for (int nt = 0; nt < 4; nt++)                                     \
                acc[mt][nt] = __builtin_amdgcn_mfma_f32_16x16x32_f16(          \
                    src[mt], bf[nt], acc[mt][nt], 0, 0, 0);                    \
    }

    LOAD_AF(afA, 0);
    LOAD_AF(afB, 1); DO_MFMA(afA, 0);
    LOAD_AF(afA, 2); DO_MFMA(afB, 1);
    LOAD_AF(afB, 3); DO_MFMA(afA, 2);
    LOAD_AF(afA, 4); DO_MFMA(afB, 3);
    LOAD_AF(afB, 5); DO_MFMA(afA, 4);
    DO_MFMA(afB, 5);
#undef LOAD_AF
#undef DO_MFMA

    __syncthreads();                     // X dead; OT2 takes over the LDS

    // ---- phase 2: acc -> OT2[o][nn*3 + t]  (row stride 784 B) ----
#pragma unroll
    for (int mt = 0; mt < 3; mt++) {
#pragma unroll
        for (int r = 0; r < 4; r++) {
            int p2 = wid * 48 + mt * 16 + l4 * 4 + r;
            int o = p2 / 3, t = p2 - 3 * (p2 / 3);
#pragma unroll
            for (int nt = 0; nt < 4; nt++) {
                int nn = nt * 16 + l15;
                *(float*)(lds + o * 784 + (nn * 3 + t) * 4) = acc[mt][nt][r];
            }
        }
    }
    __syncthreads();

    // ---- phase 3: dense readout, 768B-contiguous runs per o ----
#pragma unroll
    for (int k = 0; k < 12; k++) {
        int fid = k * 256 + tid;         // 3072 float4 tasks
        int o = fid / 48, w = fid - (fid / 48) * 48;
        float4 v = *(const float4*)(lds + o * 784 + w * 16);
        *(float4*)(ob + ((size_t)o * NPTS + n0) * 3 + w * 4) = v;
    }
}

extern "C" void kernel_launch(void* const* d_in, const int* in_sizes, int n_in,
                              void* d_out, int out_size, void* d_ws, size_t ws_size,
                              hipStream_t stream) {
    const float* feat = (const float*)d_in[0];
    const float* Wq   = (const float*)d_in[2];
    const float* Wk   = (const float*)d_in[3];
    const float* Wv   = (const float*)d_in[4];
    const float* Wout = (const float*)d_in[5];
    float* out = (float*)d_out;

    char* w8 = (char*)d_ws;                    // total ws use: ~1.35 MB
    f16*   Ab = (f16*)w8;                      //   589,824 B
    float* MS = (float*)(w8 + 589824);         //    65,536 B
    float* P  = (float*)(w8 + 655360);         //    65,536 B
    float* MX = (float*)(w8 + 720896);         //   589,824 B
    float* pl = (float*)(w8 + 1310720);        //    36,864 B

    k_mp   <<<8,            256, 0, stream>>>(Wq, Wk, Wv, Wout, MS, P);
    k_mx   <<<144,          256, 0, stream>>>(MS, MX);
    k_gram <<<BATCH * NCHG, 512, 0, stream>>>(feat, (const f32x4*)MX, pl);
    k_abig <<<1152,         256, 0, stream>>>(pl, P, Ab);
    k_apply<<<1024,         256, 0, stream>>>(feat, Ab, out);
}